// Round 5
// baseline (597.132 us; speedup 1.0000x reference)
//
#include <hip/hip_runtime.h>
#include <hip/hip_bf16.h>

typedef unsigned short u16;
typedef __attribute__((ext_vector_type(8))) short bf16x8;
typedef __attribute__((ext_vector_type(4))) float f32x4;

#define BB 16384
#define DD 2048
#define KEXT 2112   // 2048 x-cols + 16 ss cols + 48 zero pad (33 * 64)
#define HH 1024
#define EE 16
#define TOPN 409

__device__ __forceinline__ u16 f2bf(float f) {
    union { float f; unsigned u; } c; c.f = f;
    unsigned r = c.u + 0x7fffu + ((c.u >> 16) & 1u);
    return (u16)(r >> 16);
}
__device__ __forceinline__ float bf2f(u16 h) {
    union { unsigned u; float f; } c; c.u = ((unsigned)h) << 16; return c.f;
}

__device__ __forceinline__ void ld16_lds(const void* g, void* l) {
    __builtin_amdgcn_global_load_lds(
        (const __attribute__((address_space(1))) unsigned int*)g,
        (__attribute__((address_space(3))) unsigned int*)l, 16, 0, 0);
}

// ---------------- stats_prep: fused stats (blocks 0..4095) + weight prep
// (blocks 4096..5679). Prep blocks co-schedule with the latency-bound stats
// blocks, hiding the former prep_t launch. ----------------
__global__ __launch_bounds__(256)
void stats_prep(const float* __restrict__ x,
                const float* __restrict__ Wk1, const float* __restrict__ bk1,
                const float* __restrict__ Wk2, const float* __restrict__ bk2,
                float* __restrict__ stats_out, u16* __restrict__ xh, u16* __restrict__ xl,
                unsigned* __restrict__ kflags,
                const float* __restrict__ Ws1, const float* __restrict__ Wr1,
                u16* __restrict__ w1t, u16* __restrict__ wr1h, u16* __restrict__ wr1l,
                const float* __restrict__ Ws2, const float* __restrict__ Wr2,
                const float* __restrict__ pat,
                u16* __restrict__ w2t1, u16* __restrict__ wr2th, u16* __restrict__ wr2tl,
                u16* __restrict__ patTh, u16* __restrict__ patTl)
{
    __shared__ float tile[64][65];
    const int t = threadIdx.x;

    if (blockIdx.x >= 4096) {
        // ---------------- prep path ----------------
        const int e = blockIdx.x - 4096;          // 0..1583
        const int mat = e / (33 * 16);            // 0: Ws1, 1: Wr1, 2: small
        const int rem = e % (33 * 16);
        const int kt = rem % 33;
        const int nt = rem / 33;
        if (mat == 2) {
            int idx = rem * 256 + t;
            if (idx < EE * HH) {
                int ee = idx / HH, n = idx % HH;
                w2t1[idx] = f2bf(Ws2[(size_t)n * EE + ee]);
                float v = Wr2[(size_t)n * EE + ee];
                u16 h = f2bf(v);
                wr2th[idx] = h;
                wr2tl[idx] = f2bf(v - bf2f(h));
            }
            if (idx < EE * DD) {
                float v = pat[idx];   // pat is [E][D] row-major = B^T layout already
                u16 h = f2bf(v);
                patTh[idx] = h;
                patTl[idx] = f2bf(v - bf2f(h));
            }
            return;
        }
        if (mat == 0 && kt >= 32) return;
        const int k0 = kt * 64, n0 = nt * 64;
        const float* src = mat ? Wr1 : Ws1;
        const int kmax = mat ? (DD + EE) : DD;
        #pragma unroll
        for (int i = 0; i < 16; ++i) {
            int ei = i * 256 + t;
            int r = ei >> 6, c = ei & 63;
            float v = (k0 + r < kmax) ? src[(size_t)(k0 + r) * HH + n0 + c] : 0.0f;
            tile[r][c] = v;
        }
        __syncthreads();
        #pragma unroll
        for (int i = 0; i < 16; ++i) {
            int ei = i * 256 + t;
            int rn = ei >> 6, ck = ei & 63;
            float v = tile[ck][rn];
            size_t oidx = (size_t)(n0 + rn) * KEXT + k0 + ck;
            if (mat == 0) {
                w1t[oidx] = f2bf(v);
            } else {
                u16 h = f2bf(v);
                wr1h[oidx] = h;
                wr1l[oidx] = f2bf(v - bf2f(h));
            }
        }
        return;
    }

    // ---------------- stats path: 1 wave per row ----------------
    const int wid = t >> 6;
    const int lane = t & 63;
    const int row = blockIdx.x * 4 + wid;
    const float* xr = x + (size_t)row * DD;

    float v[32];
    #pragma unroll
    for (int s = 0; s < 8; ++s) {
        float4 a = *(const float4*)(xr + s * 256 + lane * 4);
        v[s*4+0]=a.x; v[s*4+1]=a.y; v[s*4+2]=a.z; v[s*4+3]=a.w;
    }

    u16* ph = xh + (size_t)row * KEXT;
    u16* pl = xl + (size_t)row * KEXT;
    #pragma unroll
    for (int s = 0; s < 8; ++s) {
        union { u16 a[4]; unsigned long long q; } H, L;
        #pragma unroll
        for (int c = 0; c < 4; ++c) {
            float f = v[s*4+c];
            u16 h = f2bf(f);
            H.a[c] = h; L.a[c] = f2bf(f - bf2f(h));
        }
        *(unsigned long long*)(ph + s*256 + lane*4) = H.q;
        *(unsigned long long*)(pl + s*256 + lane*4) = L.q;
    }
    // zero the pad/ss columns (thinAc later fills 2048..2063 with ss)
    ph[DD + lane] = 0;
    pl[DD + lane] = 0;

    float s1 = 0;
    #pragma unroll
    for (int j = 0; j < 32; ++j) s1 += v[j];
    #pragma unroll
    for (int off = 32; off >= 1; off >>= 1) s1 += __shfl_xor(s1, off);
    const float mean = s1 * (1.0f/2048.0f);

    float s2=0, s3=0, sa=0, sq=0, zc=0, mx=0;
    #pragma unroll
    for (int j = 0; j < 32; ++j) {
        float d = v[j] - mean;
        s2 += d*d; s3 += d*d*d;
        float av = fabsf(v[j]);
        sa += av; sq += v[j]*v[j];
        mx = fmaxf(mx, av);
        zc += (v[j] == 0.0f) ? 1.0f : 0.0f;
    }
    #pragma unroll
    for (int off = 32; off >= 1; off >>= 1) {
        s2 += __shfl_xor(s2, off);
        s3 += __shfl_xor(s3, off);
        sa += __shfl_xor(sa, off);
        sq += __shfl_xor(sq, off);
        zc += __shfl_xor(zc, off);
        mx = fmaxf(mx, __shfl_xor(mx, off));
    }

    // top-409 threshold: binary search in bf16 space (15 iters vs 31 in f32-bit
    // space). Ties at bf16 granularity are corrected by (TOPN-cg)*T below;
    // error ~ few ties x ulp(T)/2 -> ~4e-6 in st5, well under tolerance.
    int b[32];
    #pragma unroll
    for (int j = 0; j < 32; ++j) {
        v[j] = fabsf(v[j]);
        b[j] = (int)f2bf(v[j]);
    }
    unsigned lo = 0, hi = 0x7F80u;
    while (lo < hi) {
        unsigned mid = (lo + hi) >> 1;
        unsigned cnt = 0;
        #pragma unroll
        for (int j = 0; j < 32; ++j)
            cnt += (unsigned)__popcll(__ballot(b[j] > (int)mid));
        if (cnt < TOPN) hi = mid; else lo = mid + 1;
    }
    const float T = bf2f((u16)lo);

    float cg = 0, sg = 0;
    #pragma unroll
    for (int j = 0; j < 32; ++j) {
        if (v[j] > T) { cg += 1.0f; sg += v[j]; }
    }
    #pragma unroll
    for (int off = 32; off >= 1; off >>= 1) { cg += __shfl_xor(cg, off); sg += __shfl_xor(sg, off); }

    if (lane == 0) {
        float top = sg + ((float)TOPN - cg) * T;
        float var_u = s2 * (1.0f/2047.0f);
        float stdv = sqrtf(var_u + 1e-8f);
        float st0 = zc * (1.0f/2048.0f);
        float st1 = var_u;
        float st2 = mx;
        float st3 = sqrtf(sq);
        float st4 = (s3 * (1.0f/2048.0f)) / (stdv*stdv*stdv);
        float st5 = top / (sa + 1e-8f);
        float* so = stats_out + (size_t)row * 6;
        so[0]=st0; so[1]=st1; so[2]=st2; so[3]=st3; so[4]=st4; so[5]=st5;
        float stv[6] = {st0,st1,st2,st3,st4,st5};
        float o = bk2[0];
        #pragma unroll
        for (int i = 0; i < 16; ++i) {
            float h = bk1[i];
            #pragma unroll
            for (int f = 0; f < 6; ++f) h += stv[f] * Wk1[f*16 + i];
            o += fmaxf(h, 0.0f) * Wk2[i];
        }
        float kr = 1.0f / (1.0f + expf(-o));
        float kv = 1.0f + 3.0f * kr;
        kflags[row] = (kv < 2.0f ? 1u : 0u) | (kv < 3.0f ? 0x10000u : 0u);
    }
}

// ---------------- k-median reduce ----------------
__global__ __launch_bounds__(1024)
void kmed_kernel(const unsigned* __restrict__ kflags, int* __restrict__ counters)
{
    const int t = threadIdx.x;
    unsigned s = 0;
    for (int i = t; i < BB; i += 1024) s += kflags[i];
    #pragma unroll
    for (int off = 32; off >= 1; off >>= 1) s += __shfl_xor(s, off);
    __shared__ unsigned red[16];
    if ((t & 63) == 0) red[t >> 6] = s;
    __syncthreads();
    if (t == 0) {
        unsigned tot = 0;
        #pragma unroll
        for (int w = 0; w < 16; ++w) tot += red[w];
        counters[0] = (int)(tot & 0xFFFFu);
        counters[1] = (int)(tot >> 16);
    }
}

// ---------------- gemm_h1: h1 = relu(x@Ws1+bs1), 256x128 tile, all-fused ----------------
// 512 blocks = exactly 2/CU. Per K-iter: stage 48KB (A 256x64 + B 128x64),
// 64 MFMA/wave -> 4x the MFMA per barrier-pair of the old 128x128 tile (2x
// MAC/byte) to amortize the 2-barrier structure's drain stall.
// In-loop 3-term sims (K split across the 8 nblk peers); epilogue: h1 tile ->
// LDS bf16 (64KB) -> spec partial h1@Ws2. h1 never touches global memory.
__global__ __launch_bounds__(256, 2)
void gemm_h1(const u16* __restrict__ xh, const u16* __restrict__ xl,
             const u16* __restrict__ w1t, const float* __restrict__ bias,
             const u16* __restrict__ w2t,
             const u16* __restrict__ patTh, const u16* __restrict__ patTl,
             float* __restrict__ spec_part, float* __restrict__ sims_part)
{
    __shared__ u16 SM[32768];           // 64KB: staging uses 48KB; epilogue all 64KB
    u16* AsH = SM;                      // 256 rows x 64 k
    u16* BsH = SM + 16384;              // 128 rows x 64 k
    const int t = threadIdx.x;
    const int id = blockIdx.x;
    const int xcd = id & 7;
    const int jj = id >> 3;             // 0..63
    const int nblk = jj & 7;
    const int mgrp = jj >> 3;           // 0..7
    const int m0 = (xcd * 8 + mgrp) * 256;
    const int n0 = nblk * 128;
    const int wid = t >> 6, lane = t & 63, l16 = lane & 15, q = lane >> 4;
    const int wm = (wid & 1) * 128, wn = (wid >> 1) * 64;
    const int x7 = l16 & 7;
    const bool swave = (wid < 2);       // waves 0,1 (wm=0,128) cover all 256 rows

    f32x4 acc[8][4] = {};
    f32x4 sacc[8] = {};

    for (int it = 0; it < 32; ++it) {
        const int k0 = it * 64;
        __syncthreads();
        #pragma unroll
        for (int s = 0; s < 8; ++s) {   // A: 2048 chunk slots
            int seg = t + s * 256;
            int row = seg >> 3;
            int c = (seg & 7) ^ (row & 7);
            ld16_lds(xh + (size_t)(m0 + row) * KEXT + k0 + c * 8, (void*)(AsH + seg * 8));
        }
        #pragma unroll
        for (int s = 0; s < 4; ++s) {   // B: 1024 chunk slots
            int seg = t + s * 256;
            int row = seg >> 3;
            int c = (seg & 7) ^ (row & 7);
            ld16_lds(w1t + (size_t)(n0 + row) * KEXT + k0 + c * 8, (void*)(BsH + seg * 8));
        }
        __syncthreads();
        const bool simiter = ((it & 7) == nblk);
        #pragma unroll
        for (int h = 0; h < 2; ++h) {
            const int coff = ((4*h + q) ^ x7) * 8;
            const int gc = k0 + (4*h + q) * 8;
            bf16x8 bfh[4];
            #pragma unroll
            for (int j = 0; j < 4; ++j)
                bfh[j] = *(const bf16x8*)(BsH + (wn + 16*j + l16) * 64 + coff);
            bf16x8 pb0 = {}, pb1 = {};
            if (simiter && swave) {
                pb0 = *(const bf16x8*)(patTh + (size_t)l16 * DD + gc);
                pb1 = *(const bf16x8*)(patTl + (size_t)l16 * DD + gc);
            }
            #pragma unroll
            for (int i = 0; i < 8; ++i) {
                bf16x8 afh = *(const bf16x8*)(AsH + (wm + 16*i + l16) * 64 + coff);
                #pragma unroll
                for (int j = 0; j < 4; ++j)
                    acc[i][j] = __builtin_amdgcn_mfma_f32_16x16x32_bf16(afh, bfh[j], acc[i][j], 0, 0, 0);
                if (simiter && swave) {
                    bf16x8 al = *(const bf16x8*)(xl + (size_t)(m0 + wm + 16*i + l16) * KEXT + gc);
                    sacc[i] = __builtin_amdgcn_mfma_f32_16x16x32_bf16(afh, pb0, sacc[i], 0, 0, 0);
                    sacc[i] = __builtin_amdgcn_mfma_f32_16x16x32_bf16(afh, pb1, sacc[i], 0, 0, 0);
                    sacc[i] = __builtin_amdgcn_mfma_f32_16x16x32_bf16(al,  pb0, sacc[i], 0, 0, 0);
                }
            }
        }
    }

    // ---- epilogue: h1 tile (256x128) -> LDS bf16, spec partial = h1 @ Ws2 ----
    __syncthreads();
    u16* h1t = SM;   // 256 x 128 u16 = 64 KB
    #pragma unroll
    for (int j = 0; j < 4; ++j) {
        int col = wn + 16*j + l16;
        float bvj = bias[n0 + col];
        #pragma unroll
        for (int i = 0; i < 8; ++i)
            #pragma unroll
            for (int r = 0; r < 4; ++r) {
                int row = wm + 16*i + q*4 + r;
                float vv = acc[i][j][r] + bvj;
                vv = vv > 0.0f ? vv : 0.0f;
                h1t[row * 128 + col] = f2bf(vv);
            }
    }
    __syncthreads();
    const int mb = wid * 64;     // each wave: 64 rows x 16 experts, K=128
    f32x4 s16[4] = {};
    #pragma unroll
    for (int kk = 0; kk < 4; ++kk) {
        bf16x8 wb = *(const bf16x8*)(w2t + (size_t)l16 * HH + n0 + kk*32 + q*8);
        #pragma unroll
        for (int i2 = 0; i2 < 4; ++i2) {
            bf16x8 af = *(const bf16x8*)(h1t + (mb + i2*16 + l16) * 128 + kk*32 + q*8);
            s16[i2] = __builtin_amdgcn_mfma_f32_16x16x32_bf16(af, wb, s16[i2], 0, 0, 0);
        }
    }
    #pragma unroll
    for (int i2 = 0; i2 < 4; ++i2)
        #pragma unroll
        for (int r = 0; r < 4; ++r) {
            int row = m0 + mb + i2*16 + q*4 + r;
            spec_part[((size_t)nblk * BB + row) * EE + l16] = s16[i2][r];
        }
    if (swave) {
        #pragma unroll
        for (int i = 0; i < 8; ++i)
            #pragma unroll
            for (int r = 0; r < 4; ++r) {
                int row = m0 + wm + 16*i + q*4 + r;
                sims_part[((size_t)nblk * BB + row) * EE + l16] = sacc[i][r];
            }
    }
}

// ---------------- gemm_h2: h2 = relu(ri@Wr1+br1) 3-term; fused logits ----------------
// h2 never touches global: epilogue rounds the 128x128 tile to bf16 hi/lo in LDS
// (identical rounding path to the old ha/hb store->load) and contracts the
// block's n-slice against Wr2 (3-term), writing per-nblk f32 logit partials.
__global__ __launch_bounds__(256)
void gemm_h2(const u16* __restrict__ Ah, const u16* __restrict__ Al,
             const u16* __restrict__ Bh, const u16* __restrict__ Bl,
             const float* __restrict__ bias,
             const u16* __restrict__ wr2th, const u16* __restrict__ wr2tl,
             float* __restrict__ lg_part)
{
    __shared__ u16 SM[4*8192];
    u16* AsH = SM;
    u16* BsH = SM + 8192;
    u16* AsL = SM + 2*8192;
    u16* BsL = SM + 3*8192;
    const int t = threadIdx.x;
    const int id = blockIdx.x;
    const int xcd = id & 7;
    const int jj = id >> 3;
    const int nblk = jj & 7;
    const int mgrp = jj >> 3;
    const int m0 = (xcd * 16 + mgrp) * 128;
    const int n0 = nblk * 128;
    const int wid = t >> 6, lane = t & 63, l16 = lane & 15, q = lane >> 4;
    const int wm = (wid & 1) * 64, wn = (wid >> 1) * 64;
    const int x7 = l16 & 7;

    f32x4 acc[4][4] = {};

    for (int it = 0; it < 33; ++it) {
        const int k0 = it * 64;
        __syncthreads();
        #pragma unroll
        for (int s = 0; s < 4; ++s) {
            int seg = t + s * 256;
            int row = seg >> 3;
            int c = (seg & 7) ^ (row & 7);
            size_t goff = (size_t)k0 + c * 8;
            size_t aoff = (size_t)(m0 + row) * KEXT + goff;
            size_t boff = (size_t)(n0 + row) * KEXT + goff;
            ld16_lds(Ah + aoff, (void*)(AsH + seg * 8));
            ld16_lds(Bh + boff, (void*)(BsH + seg * 8));
            ld16_lds(Al + aoff, (void*)(AsL + seg * 8));
            ld16_lds(Bl + boff, (void*)(BsL + seg * 8));
        }
        __syncthreads();
        #pragma unroll
        for (int h = 0; h < 2; ++h) {
            const int coff = ((4*h + q) ^ x7) * 8;
            bf16x8 afh[4], bfh[4], afl[4], bfl[4];
            #pragma unroll
            for (int i = 0; i < 4; ++i) {
                const int ra = (wm + 16*i + l16) * 64 + coff;
                const int rb = (wn + 16*i + l16) * 64 + coff;
                afh[i] = *(const bf16x8*)(AsH + ra);
                bfh[i] = *(const bf16x8*)(BsH + rb);
                afl[i] = *(const bf16x8*)(AsL + ra);
                bfl[i] = *(const bf16x8*)(BsL + rb);
            }
            #pragma unroll
            for (int i = 0; i < 4; ++i)
                #pragma unroll
                for (int j = 0; j < 4; ++j) {
                    acc[i][j] = __builtin_amdgcn_mfma_f32_16x16x32_bf16(afh[i], bfh[j], acc[i][j], 0, 0, 0);
                    acc[i][j] = __builtin_amdgcn_mfma_f32_16x16x32_bf16(afh[i], bfl[j], acc[i][j], 0, 0, 0);
                    acc[i][j] = __builtin_amdgcn_mfma_f32_16x16x32_bf16(afl[i], bfh[j], acc[i][j], 0, 0, 0);
                }
        }
    }

    // ---- epilogue: h2 tile (hi/lo) -> LDS, logits partial = h2 @ Wr2 (3-term) ----
    __syncthreads();
    u16* h2h = SM;            // 128x128 u16 = 32 KB
    u16* h2l = SM + 16384;    // 128x128 u16 = 32 KB
    #pragma unroll
    for (int j = 0; j < 4; ++j) {
        int col = wn + 16*j + l16;
        float bvj = bias[n0 + col];
        #pragma unroll
        for (int i = 0; i < 4; ++i)
            #pragma unroll
            for (int r = 0; r < 4; ++r) {
                int row = wm + 16*i + q*4 + r;
                float vv = acc[i][j][r] + bvj;
                vv = vv > 0.0f ? vv : 0.0f;
                u16 h = f2bf(vv);
                h2h[row * 128 + col] = h;
                h2l[row * 128 + col] = f2bf(vv - bf2f(h));
            }
    }
    __syncthreads();
    const int mb = wid * 32;
    f32x4 lacc[2] = {};
    #pragma unroll
    for (int kk = 0; kk < 4; ++kk) {
        bf16x8 wbh = *(const bf16x8*)(wr2th + (size_t)l16 * HH + n0 + kk*32 + q*8);
        bf16x8 wbl = *(const bf16x8*)(wr2tl + (size_t)l16 * HH + n0 + kk*32 + q*8);
        #pragma unroll
        for (int i2 = 0; i2 < 2; ++i2) {
            bf16x8 ah = *(const bf16x8*)(h2h + (mb + i2*16 + l16) * 128 + kk*32 + q*8);
            bf16x8 al = *(const bf16x8*)(h2l + (mb + i2*16 + l16) * 128 + kk*32 + q*8);
            lacc[i2] = __builtin_amdgcn_mfma_f32_16x16x32_bf16(ah, wbh, lacc[i2], 0, 0, 0);
            lacc[i2] = __builtin_amdgcn_mfma_f32_16x16x32_bf16(ah, wbl, lacc[i2], 0, 0, 0);
            lacc[i2] = __builtin_amdgcn_mfma_f32_16x16x32_bf16(al, wbh, lacc[i2], 0, 0, 0);
        }
    }
    #pragma unroll
    for (int i2 = 0; i2 < 2; ++i2)
        #pragma unroll
        for (int r = 0; r < 4; ++r) {
            int row = m0 + mb + i2*16 + q*4 + r;
            lg_part[((size_t)nblk * BB + row) * EE + l16] = lacc[i2][r];
        }
}

// ---------------- thinAc: combine sims+spec partials -> ss sigmoid -> xh/xl cols ----------------
__global__ __launch_bounds__(64)
void thinAc(const float* __restrict__ spec_part, const float* __restrict__ sims_part,
            const float* __restrict__ bs2,
            u16* __restrict__ xh_w, u16* __restrict__ xl_w)
{
    const int lane = threadIdx.x & 63;
    const int l16 = lane & 15, q = lane >> 4;
    const int m0 = blockIdx.x * 16;
    const float b2 = bs2[l16];
    #pragma unroll
    for (int r = 0; r < 4; ++r) {
        int row = m0 + q*4 + r;
        float sp = 0.0f;
        #pragma unroll
        for (int p = 0; p < 8; ++p) {
            sp += spec_part[((size_t)p * BB + row) * EE + l16];
            sp += sims_part[((size_t)p * BB + row) * EE + l16];
        }
        float ssv = 1.0f / (1.0f + expf(-(sp + b2)));
        u16 h = f2bf(ssv);
        xh_w[(size_t)row * KEXT + DD + l16] = h;
        xl_w[(size_t)row * KEXT + DD + l16] = f2bf(ssv - bf2f(h));
    }
}

// ---------------- thinBc: combine logit partials; softmax+top4+gates ----------------
__global__ __launch_bounds__(64)
void thinBc(const float* __restrict__ lg_part,
            const float* __restrict__ br2, const int* __restrict__ counters,
            float* __restrict__ out_gates, float* __restrict__ out_idx,
            float* __restrict__ out_probs)
{
    const int lane = threadIdx.x & 63;
    const int l16 = lane & 15, q = lane >> 4;
    const int m0 = blockIdx.x * 16;
    const float b2 = br2[l16];
    const int c2 = counters[0], c3 = counters[1];
    const int k = (c2 >= 8192) ? 1 : ((c3 >= 8192) ? 2 : 3);
    #pragma unroll
    for (int r = 0; r < 4; ++r) {
        const int row = m0 + q*4 + r;
        float lg = b2;
        #pragma unroll
        for (int p = 0; p < 8; ++p)
            lg += lg_part[((size_t)p * BB + row) * EE + l16];
        float mxv = lg;
        #pragma unroll
        for (int off = 1; off < 16; off <<= 1) mxv = fmaxf(mxv, __shfl_xor(mxv, off));
        float e = expf(lg - mxv);
        float den = e;
        #pragma unroll
        for (int off = 1; off < 16; off <<= 1) den += __shfl_xor(den, off);
        float p = e / den;
        out_probs[(size_t)row * EE + l16] = p;
        int kcur = (int)((__float_as_uint(p) & ~15u) | (15u - (unsigned)l16));
        float tv[4]; int ti[4];
        #pragma unroll
        for (int s = 0; s < 4; ++s) {
            int kk = kcur;
            #pragma unroll
            for (int off = 1; off < 16; off <<= 1) kk = max(kk, __shfl_xor(kk, off));
            int widx = 15 - (kk & 15);
            ti[s] = widx;
            tv[s] = __shfl(p, q * 16 + widx);
            if (l16 == widx) kcur = 0;
        }
        float den2 = 0.0f;
        float g[4];
        #pragma unroll
        for (int s = 0; s < 4; ++s) {
            g[s] = expf(tv[s] - tv[0]);
            if (s < k) den2 += g[s];
        }
        if (l16 < 4) {
            out_gates[(size_t)row * 4 + l16] = (l16 < k) ? g[l16] / den2 : 0.0f;
            out_idx[(size_t)row * 4 + l16] = (float)ti[l16];
        }
    }
}

// ---------------- host launch ----------------
extern "C" void kernel_launch(void* const* d_in, const int* in_sizes, int n_in,
                              void* d_out, int out_size, void* d_ws, size_t ws_size,
                              hipStream_t stream) {
    const float* x   = (const float*)d_in[0];
    const float* pat = (const float*)d_in[1];
    const float* Ws1 = (const float*)d_in[2];
    const float* bs1 = (const float*)d_in[3];
    const float* Ws2 = (const float*)d_in[4];
    const float* bs2 = (const float*)d_in[5];
    const float* Wr1 = (const float*)d_in[6];
    const float* br1 = (const float*)d_in[7];
    const float* Wr2 = (const float*)d_in[8];
    const float* br2 = (const float*)d_in[9];
    const float* Wk1 = (const float*)d_in[10];
    const float* bk1 = (const float*)d_in[11];
    const float* Wk2 = (const float*)d_in[12];
    const float* bk2 = (const float*)d_in[13];

    char* ws = (char*)d_ws;
    size_t off = 0;
    auto alloc = [&](size_t bytes) { char* p = ws + off; off += (bytes + 255) & ~(size_t)255; return p; };
    u16* xh     = (u16*)alloc((size_t)BB * KEXT * 2);
    u16* xl     = (u16*)alloc((size_t)BB * KEXT * 2);
    u16* w1t    = (u16*)alloc((size_t)HH * KEXT * 2);
    u16* wr1h   = (u16*)alloc((size_t)HH * KEXT * 2);
    u16* wr1l   = (u16*)alloc((size_t)HH * KEXT * 2);
    u16* w2t1   = (u16*)alloc((size_t)EE * HH * 2);
    u16* wr2th  = (u16*)alloc((size_t)EE * HH * 2);
    u16* wr2tl  = (u16*)alloc((size_t)EE * HH * 2);
    u16* patTh  = (u16*)alloc((size_t)EE * DD * 2);
    u16* patTl  = (u16*)alloc((size_t)EE * DD * 2);
    float* partA = (float*)alloc((size_t)16 * BB * EE * 4);  // spec(8) + sims(8) partials
    float* partB = (float*)alloc((size_t)8  * BB * EE * 4);  // logit partials
    unsigned* kflags = (unsigned*)alloc((size_t)BB * 4);
    int* cnt      = (int*)alloc(64);

    float* spec_part = partA;
    float* sims_part = partA + (size_t)8 * BB * EE;
    float* lg_part   = partB;

    float* out        = (float*)d_out;
    float* out_gates  = out;
    float* out_idx    = out + (size_t)BB * 4;
    float* out_probs  = out + (size_t)BB * 8;
    float* out_stats  = out + (size_t)BB * 24;

    // stats (4096 blocks) + weight prep (1584 blocks) co-scheduled
    stats_prep<<<4096 + 1584, 256, 0, stream>>>(
        x, Wk1, bk1, Wk2, bk2, out_stats, xh, xl, kflags,
        Ws1, Wr1, w1t, wr1h, wr1l, Ws2, Wr2, pat,
        w2t1, wr2th, wr2tl, patTh, patTl);

    kmed_kernel<<<1, 1024, 0, stream>>>(kflags, cnt);

    // h1 = relu(x@Ws1 + bs1), 256x128 tile, fused 3-term sims + spec partials
    gemm_h1<<<512, 256, 0, stream>>>(xh, xl, w1t, bs1, w2t1, patTh, patTl,
                                     spec_part, sims_part);

    // combine partials -> ss sigmoid -> xh/xl cols 2048..2063
    thinAc<<<BB/16, 64, 0, stream>>>(spec_part, sims_part, bs2, xh, xl);

    // h2 = relu(ri@Wr1 + br1) 3-term with fused logit partials (h2 never hits global)
    gemm_h2<<<1024, 256, 0, stream>>>(xh, xl, wr1h, wr1l, br1, wr2th, wr2tl, lg_part);

    // combine logits + softmax + top4 + gates
    thinBc<<<BB/16, 64, 0, stream>>>(lg_part, br2, cnt, out_gates, out_idx, out_probs);
}

// Round 6
// 549.420 us; speedup vs baseline: 1.0868x; 1.0868x over previous
//
#include <hip/hip_runtime.h>
#include <hip/hip_bf16.h>

typedef unsigned short u16;
typedef __attribute__((ext_vector_type(8))) short bf16x8;
typedef __attribute__((ext_vector_type(4))) float f32x4;

#define BB 16384
#define DD 2048
#define KEXT 2112   // 2048 x-cols + 16 ss cols + 48 zero pad (33 * 64)
#define HH 1024
#define EE 16
#define TOPN 409

__device__ __forceinline__ u16 f2bf(float f) {
    union { float f; unsigned u; } c; c.f = f;
    unsigned r = c.u + 0x7fffu + ((c.u >> 16) & 1u);
    return (u16)(r >> 16);
}
__device__ __forceinline__ float bf2f(u16 h) {
    union { unsigned u; float f; } c; c.u = ((unsigned)h) << 16; return c.f;
}

__device__ __forceinline__ void ld16_lds(const void* g, void* l) {
    __builtin_amdgcn_global_load_lds(
        (const __attribute__((address_space(1))) unsigned int*)g,
        (__attribute__((address_space(3))) unsigned int*)l, 16, 0, 0);
}

// epilogue LDS swizzle: XOR the 16-B chunk index (col>>3, 4 bits) with row&7.
// Write side (scalar u16 stores) and read side (ds_read_b128) apply the same
// XOR -> per-row bijective; 16-lane read groups land 2 lanes/bank (free).
__device__ __forceinline__ int epswz(int row, int col) {
    return (((col >> 3) ^ (row & 7)) << 3) | (col & 7);
}

// ---------------- stats_prep: fused stats (blocks 0..4095) + weight prep
// (blocks 4096..5679). Prep blocks co-schedule with the latency-bound stats
// blocks, hiding the former prep_t launch. ----------------
__global__ __launch_bounds__(256)
void stats_prep(const float* __restrict__ x,
                const float* __restrict__ Wk1, const float* __restrict__ bk1,
                const float* __restrict__ Wk2, const float* __restrict__ bk2,
                float* __restrict__ stats_out, u16* __restrict__ xh, u16* __restrict__ xl,
                unsigned* __restrict__ kflags,
                const float* __restrict__ Ws1, const float* __restrict__ Wr1,
                u16* __restrict__ w1t, u16* __restrict__ wr1h, u16* __restrict__ wr1l,
                const float* __restrict__ Ws2, const float* __restrict__ Wr2,
                const float* __restrict__ pat,
                u16* __restrict__ w2t1, u16* __restrict__ wr2th, u16* __restrict__ wr2tl,
                u16* __restrict__ patTh, u16* __restrict__ patTl)
{
    __shared__ float tile[64][65];
    const int t = threadIdx.x;

    if (blockIdx.x >= 4096) {
        // ---------------- prep path ----------------
        const int e = blockIdx.x - 4096;          // 0..1583
        const int mat = e / (33 * 16);            // 0: Ws1, 1: Wr1, 2: small
        const int rem = e % (33 * 16);
        const int kt = rem % 33;
        const int nt = rem / 33;
        if (mat == 2) {
            int idx = rem * 256 + t;
            if (idx < EE * HH) {
                int ee = idx / HH, n = idx % HH;
                w2t1[idx] = f2bf(Ws2[(size_t)n * EE + ee]);
                float v = Wr2[(size_t)n * EE + ee];
                u16 h = f2bf(v);
                wr2th[idx] = h;
                wr2tl[idx] = f2bf(v - bf2f(h));
            }
            if (idx < EE * DD) {
                float v = pat[idx];   // pat is [E][D] row-major = B^T layout already
                u16 h = f2bf(v);
                patTh[idx] = h;
                patTl[idx] = f2bf(v - bf2f(h));
            }
            return;
        }
        if (mat == 0 && kt >= 32) return;
        const int k0 = kt * 64, n0 = nt * 64;
        const float* src = mat ? Wr1 : Ws1;
        const int kmax = mat ? (DD + EE) : DD;
        #pragma unroll
        for (int i = 0; i < 16; ++i) {
            int ei = i * 256 + t;
            int r = ei >> 6, c = ei & 63;
            float v = (k0 + r < kmax) ? src[(size_t)(k0 + r) * HH + n0 + c] : 0.0f;
            tile[r][c] = v;
        }
        __syncthreads();
        #pragma unroll
        for (int i = 0; i < 16; ++i) {
            int ei = i * 256 + t;
            int rn = ei >> 6, ck = ei & 63;
            float v = tile[ck][rn];
            size_t oidx = (size_t)(n0 + rn) * KEXT + k0 + ck;
            if (mat == 0) {
                w1t[oidx] = f2bf(v);
            } else {
                u16 h = f2bf(v);
                wr1h[oidx] = h;
                wr1l[oidx] = f2bf(v - bf2f(h));
            }
        }
        return;
    }

    // ---------------- stats path: 1 wave per row ----------------
    const int wid = t >> 6;
    const int lane = t & 63;
    const int row = blockIdx.x * 4 + wid;
    const float* xr = x + (size_t)row * DD;

    float v[32];
    #pragma unroll
    for (int s = 0; s < 8; ++s) {
        float4 a = *(const float4*)(xr + s * 256 + lane * 4);
        v[s*4+0]=a.x; v[s*4+1]=a.y; v[s*4+2]=a.z; v[s*4+3]=a.w;
    }

    u16* ph = xh + (size_t)row * KEXT;
    u16* pl = xl + (size_t)row * KEXT;
    #pragma unroll
    for (int s = 0; s < 8; ++s) {
        union { u16 a[4]; unsigned long long q; } H, L;
        #pragma unroll
        for (int c = 0; c < 4; ++c) {
            float f = v[s*4+c];
            u16 h = f2bf(f);
            H.a[c] = h; L.a[c] = f2bf(f - bf2f(h));
        }
        *(unsigned long long*)(ph + s*256 + lane*4) = H.q;
        *(unsigned long long*)(pl + s*256 + lane*4) = L.q;
    }
    // zero the pad/ss columns (thinAc later fills 2048..2063 with ss)
    ph[DD + lane] = 0;
    pl[DD + lane] = 0;

    float s1 = 0;
    #pragma unroll
    for (int j = 0; j < 32; ++j) s1 += v[j];
    #pragma unroll
    for (int off = 32; off >= 1; off >>= 1) s1 += __shfl_xor(s1, off);
    const float mean = s1 * (1.0f/2048.0f);

    float s2=0, s3=0, sa=0, sq=0, zc=0, mx=0;
    #pragma unroll
    for (int j = 0; j < 32; ++j) {
        float d = v[j] - mean;
        s2 += d*d; s3 += d*d*d;
        float av = fabsf(v[j]);
        sa += av; sq += v[j]*v[j];
        mx = fmaxf(mx, av);
        zc += (v[j] == 0.0f) ? 1.0f : 0.0f;
    }
    #pragma unroll
    for (int off = 32; off >= 1; off >>= 1) {
        s2 += __shfl_xor(s2, off);
        s3 += __shfl_xor(s3, off);
        sa += __shfl_xor(sa, off);
        sq += __shfl_xor(sq, off);
        zc += __shfl_xor(zc, off);
        mx = fmaxf(mx, __shfl_xor(mx, off));
    }

    // exact top-409 threshold: binary search on f32 bit patterns (31 iters)
    #pragma unroll
    for (int j = 0; j < 32; ++j) v[j] = fabsf(v[j]);

    unsigned lo = 0, hi = 0x7F800000u;
    while (lo < hi) {
        unsigned mid = (lo + hi) >> 1;
        float midf = __uint_as_float(mid);
        unsigned cnt = 0;
        #pragma unroll
        for (int j = 0; j < 32; ++j)
            cnt += (unsigned)__popcll(__ballot(v[j] > midf));
        if (cnt < TOPN) hi = mid; else lo = mid + 1;
    }
    const float T = __uint_as_float(lo);

    float cg = 0, sg = 0;
    #pragma unroll
    for (int j = 0; j < 32; ++j) {
        if (v[j] > T) { cg += 1.0f; sg += v[j]; }
    }
    #pragma unroll
    for (int off = 32; off >= 1; off >>= 1) { cg += __shfl_xor(cg, off); sg += __shfl_xor(sg, off); }

    if (lane == 0) {
        float top = sg + ((float)TOPN - cg) * T;
        float var_u = s2 * (1.0f/2047.0f);
        float stdv = sqrtf(var_u + 1e-8f);
        float st0 = zc * (1.0f/2048.0f);
        float st1 = var_u;
        float st2 = mx;
        float st3 = sqrtf(sq);
        float st4 = (s3 * (1.0f/2048.0f)) / (stdv*stdv*stdv);
        float st5 = top / (sa + 1e-8f);
        float* so = stats_out + (size_t)row * 6;
        so[0]=st0; so[1]=st1; so[2]=st2; so[3]=st3; so[4]=st4; so[5]=st5;
        float stv[6] = {st0,st1,st2,st3,st4,st5};
        float o = bk2[0];
        #pragma unroll
        for (int i = 0; i < 16; ++i) {
            float h = bk1[i];
            #pragma unroll
            for (int f = 0; f < 6; ++f) h += stv[f] * Wk1[f*16 + i];
            o += fmaxf(h, 0.0f) * Wk2[i];
        }
        float kr = 1.0f / (1.0f + expf(-o));
        float kv = 1.0f + 3.0f * kr;
        kflags[row] = (kv < 2.0f ? 1u : 0u) | (kv < 3.0f ? 0x10000u : 0u);
    }
}

// ---------------- k-median reduce ----------------
__global__ __launch_bounds__(1024)
void kmed_kernel(const unsigned* __restrict__ kflags, int* __restrict__ counters)
{
    const int t = threadIdx.x;
    unsigned s = 0;
    for (int i = t; i < BB; i += 1024) s += kflags[i];
    #pragma unroll
    for (int off = 32; off >= 1; off >>= 1) s += __shfl_xor(s, off);
    __shared__ unsigned red[16];
    if ((t & 63) == 0) red[t >> 6] = s;
    __syncthreads();
    if (t == 0) {
        unsigned tot = 0;
        #pragma unroll
        for (int w = 0; w < 16; ++w) tot += red[w];
        counters[0] = (int)(tot & 0xFFFFu);
        counters[1] = (int)(tot >> 16);
    }
}

// ---------------- gemm_h1: h1 = relu(x@Ws1+bs1), 128x128 tile, all-fused ----------------
// In-loop: 3-term sims = x@patT on waves 0,1; K split across the 8 nblk peer
// blocks via (it&7)==nblk. Epilogue: h1 tile -> LDS bf16 (epswz swizzled) ->
// spec partial h1@Ws2. h1 never touches global memory.
__global__ __launch_bounds__(256)
void gemm_h1(const u16* __restrict__ xh, const u16* __restrict__ xl,
             const u16* __restrict__ w1t, const float* __restrict__ bias,
             const u16* __restrict__ w2t,
             const u16* __restrict__ patTh, const u16* __restrict__ patTl,
             float* __restrict__ spec_part, float* __restrict__ sims_part)
{
    __shared__ u16 SM[2*8192];
    u16* AsH = SM;
    u16* BsH = SM + 8192;
    const int t = threadIdx.x;
    const int id = blockIdx.x;
    const int xcd = id & 7;
    const int jj = id >> 3;
    const int nblk = jj & 7;
    const int mgrp = jj >> 3;
    const int m0 = (xcd * 16 + mgrp) * 128;
    const int n0 = nblk * 128;
    const int wid = t >> 6, lane = t & 63, l16 = lane & 15, q = lane >> 4;
    const int wm = (wid & 1) * 64, wn = (wid >> 1) * 64;
    const int x7 = l16 & 7;
    const bool swave = (wid < 2);   // waves 0,1 own sims (wm = 0, 64)

    f32x4 acc[4][4] = {};
    f32x4 sacc[4] = {};

    for (int it = 0; it < 32; ++it) {
        const int k0 = it * 64;
        __syncthreads();
        #pragma unroll
        for (int s = 0; s < 4; ++s) {
            int seg = t + s * 256;
            int row = seg >> 3;
            int c = (seg & 7) ^ (row & 7);
            size_t goff = (size_t)k0 + c * 8;
            ld16_lds(xh  + (size_t)(m0 + row) * KEXT + goff, (void*)(AsH + seg * 8));
            ld16_lds(w1t + (size_t)(n0 + row) * KEXT + goff, (void*)(BsH + seg * 8));
        }
        __syncthreads();
        const bool simiter = ((it & 7) == nblk);
        #pragma unroll
        for (int h = 0; h < 2; ++h) {
            const int coff = ((4*h + q) ^ x7) * 8;
            bf16x8 afh[4], bfh[4];
            #pragma unroll
            for (int i = 0; i < 4; ++i) {
                afh[i] = *(const bf16x8*)(AsH + (wm + 16*i + l16) * 64 + coff);
                bfh[i] = *(const bf16x8*)(BsH + (wn + 16*i + l16) * 64 + coff);
            }
            #pragma unroll
            for (int i = 0; i < 4; ++i)
                #pragma unroll
                for (int j = 0; j < 4; ++j)
                    acc[i][j] = __builtin_amdgcn_mfma_f32_16x16x32_bf16(afh[i], bfh[j], acc[i][j], 0, 0, 0);
            if (simiter && swave) {
                // global k-chunk for this (h,q) — LDS swizzle cancels: chunk = 4h+q
                const int gc = k0 + (4*h + q) * 8;
                bf16x8 pb0 = *(const bf16x8*)(patTh + (size_t)l16 * DD + gc);
                bf16x8 pb1 = *(const bf16x8*)(patTl + (size_t)l16 * DD + gc);
                #pragma unroll
                for (int i = 0; i < 4; ++i) {
                    bf16x8 al = *(const bf16x8*)(xl + (size_t)(m0 + wm + 16*i + l16) * KEXT + gc);
                    sacc[i] = __builtin_amdgcn_mfma_f32_16x16x32_bf16(afh[i], pb0, sacc[i], 0, 0, 0);
                    sacc[i] = __builtin_amdgcn_mfma_f32_16x16x32_bf16(afh[i], pb1, sacc[i], 0, 0, 0);
                    sacc[i] = __builtin_amdgcn_mfma_f32_16x16x32_bf16(al,     pb0, sacc[i], 0, 0, 0);
                }
            }
        }
    }

    // ---- epilogue: h1 tile -> LDS (bf16, epswz), spec partial = h1 @ Ws2 ----
    __syncthreads();
    u16* h1t = SM;   // 128 x 128 u16 = 32 KB
    #pragma unroll
    for (int j = 0; j < 4; ++j) {
        int col = wn + 16*j + l16;
        float bvj = bias[n0 + col];
        #pragma unroll
        for (int i = 0; i < 4; ++i)
            #pragma unroll
            for (int r = 0; r < 4; ++r) {
                int row = wm + 16*i + q*4 + r;
                float vv = acc[i][j][r] + bvj;
                vv = vv > 0.0f ? vv : 0.0f;
                h1t[row * 128 + epswz(row, col)] = f2bf(vv);
            }
    }
    __syncthreads();
    const int mb = wid * 32;     // each wave: 32 rows x 16 experts, K=128
    f32x4 s16[2] = {};
    #pragma unroll
    for (int kk = 0; kk < 4; ++kk) {
        bf16x8 wb = *(const bf16x8*)(w2t + (size_t)l16 * HH + n0 + kk*32 + q*8);
        #pragma unroll
        for (int i2 = 0; i2 < 2; ++i2) {
            const int row = mb + i2*16 + l16;
            bf16x8 af = *(const bf16x8*)(h1t + row * 128 + (((kk*4 + q) ^ (row & 7)) << 3));
            s16[i2] = __builtin_amdgcn_mfma_f32_16x16x32_bf16(af, wb, s16[i2], 0, 0, 0);
        }
    }
    #pragma unroll
    for (int i2 = 0; i2 < 2; ++i2)
        #pragma unroll
        for (int r = 0; r < 4; ++r) {
            int row = m0 + mb + i2*16 + q*4 + r;
            spec_part[((size_t)nblk * BB + row) * EE + l16] = s16[i2][r];
        }
    if (swave) {
        #pragma unroll
        for (int i = 0; i < 4; ++i)
            #pragma unroll
            for (int r = 0; r < 4; ++r) {
                int row = m0 + wm + 16*i + q*4 + r;
                sims_part[((size_t)nblk * BB + row) * EE + l16] = sacc[i][r];
            }
    }
}

// ---------------- gemm_h2: h2 = relu(ri@Wr1+br1) 3-term; fused logits ----------------
// h2 never touches global: epilogue rounds the 128x128 tile to bf16 hi/lo in LDS
// (epswz swizzled; identical rounding path to the old ha/hb store->load) and
// contracts the block's n-slice against Wr2 (3-term), writing f32 logit partials.
__global__ __launch_bounds__(256)
void gemm_h2(const u16* __restrict__ Ah, const u16* __restrict__ Al,
             const u16* __restrict__ Bh, const u16* __restrict__ Bl,
             const float* __restrict__ bias,
             const u16* __restrict__ wr2th, const u16* __restrict__ wr2tl,
             float* __restrict__ lg_part)
{
    __shared__ u16 SM[4*8192];
    u16* AsH = SM;
    u16* BsH = SM + 8192;
    u16* AsL = SM + 2*8192;
    u16* BsL = SM + 3*8192;
    const int t = threadIdx.x;
    const int id = blockIdx.x;
    const int xcd = id & 7;
    const int jj = id >> 3;
    const int nblk = jj & 7;
    const int mgrp = jj >> 3;
    const int m0 = (xcd * 16 + mgrp) * 128;
    const int n0 = nblk * 128;
    const int wid = t >> 6, lane = t & 63, l16 = lane & 15, q = lane >> 4;
    const int wm = (wid & 1) * 64, wn = (wid >> 1) * 64;
    const int x7 = l16 & 7;

    f32x4 acc[4][4] = {};

    for (int it = 0; it < 33; ++it) {
        const int k0 = it * 64;
        __syncthreads();
        #pragma unroll
        for (int s = 0; s < 4; ++s) {
            int seg = t + s * 256;
            int row = seg >> 3;
            int c = (seg & 7) ^ (row & 7);
            size_t goff = (size_t)k0 + c * 8;
            size_t aoff = (size_t)(m0 + row) * KEXT + goff;
            size_t boff = (size_t)(n0 + row) * KEXT + goff;
            ld16_lds(Ah + aoff, (void*)(AsH + seg * 8));
            ld16_lds(Bh + boff, (void*)(BsH + seg * 8));
            ld16_lds(Al + aoff, (void*)(AsL + seg * 8));
            ld16_lds(Bl + boff, (void*)(BsL + seg * 8));
        }
        __syncthreads();
        #pragma unroll
        for (int h = 0; h < 2; ++h) {
            const int coff = ((4*h + q) ^ x7) * 8;
            bf16x8 afh[4], bfh[4], afl[4], bfl[4];
            #pragma unroll
            for (int i = 0; i < 4; ++i) {
                const int ra = (wm + 16*i + l16) * 64 + coff;
                const int rb = (wn + 16*i + l16) * 64 + coff;
                afh[i] = *(const bf16x8*)(AsH + ra);
                bfh[i] = *(const bf16x8*)(BsH + rb);
                afl[i] = *(const bf16x8*)(AsL + ra);
                bfl[i] = *(const bf16x8*)(BsL + rb);
            }
            #pragma unroll
            for (int i = 0; i < 4; ++i)
                #pragma unroll
                for (int j = 0; j < 4; ++j) {
                    acc[i][j] = __builtin_amdgcn_mfma_f32_16x16x32_bf16(afh[i], bfh[j], acc[i][j], 0, 0, 0);
                    acc[i][j] = __builtin_amdgcn_mfma_f32_16x16x32_bf16(afh[i], bfl[j], acc[i][j], 0, 0, 0);
                    acc[i][j] = __builtin_amdgcn_mfma_f32_16x16x32_bf16(afl[i], bfh[j], acc[i][j], 0, 0, 0);
                }
        }
    }

    // ---- epilogue: h2 tile (hi/lo, epswz) -> LDS, logits partial (3-term) ----
    __syncthreads();
    u16* h2h = SM;            // 128x128 u16 = 32 KB
    u16* h2l = SM + 16384;    // 128x128 u16 = 32 KB
    #pragma unroll
    for (int j = 0; j < 4; ++j) {
        int col = wn + 16*j + l16;
        float bvj = bias[n0 + col];
        #pragma unroll
        for (int i = 0; i < 4; ++i)
            #pragma unroll
            for (int r = 0; r < 4; ++r) {
                int row = wm + 16*i + q*4 + r;
                float vv = acc[i][j][r] + bvj;
                vv = vv > 0.0f ? vv : 0.0f;
                u16 h = f2bf(vv);
                const int sc = epswz(row, col);
                h2h[row * 128 + sc] = h;
                h2l[row * 128 + sc] = f2bf(vv - bf2f(h));
            }
    }
    __syncthreads();
    const int mb = wid * 32;
    f32x4 lacc[2] = {};
    #pragma unroll
    for (int kk = 0; kk < 4; ++kk) {
        bf16x8 wbh = *(const bf16x8*)(wr2th + (size_t)l16 * HH + n0 + kk*32 + q*8);
        bf16x8 wbl = *(const bf16x8*)(wr2tl + (size_t)l16 * HH + n0 + kk*32 + q*8);
        #pragma unroll
        for (int i2 = 0; i2 < 2; ++i2) {
            const int row = mb + i2*16 + l16;
            const int sco = (((kk*4 + q) ^ (row & 7)) << 3);
            bf16x8 ah = *(const bf16x8*)(h2h + row * 128 + sco);
            bf16x8 al = *(const bf16x8*)(h2l + row * 128 + sco);
            lacc[i2] = __builtin_amdgcn_mfma_f32_16x16x32_bf16(ah, wbh, lacc[i2], 0, 0, 0);
            lacc[i2] = __builtin_amdgcn_mfma_f32_16x16x32_bf16(ah, wbl, lacc[i2], 0, 0, 0);
            lacc[i2] = __builtin_amdgcn_mfma_f32_16x16x32_bf16(al, wbh, lacc[i2], 0, 0, 0);
        }
    }
    #pragma unroll
    for (int i2 = 0; i2 < 2; ++i2)
        #pragma unroll
        for (int r = 0; r < 4; ++r) {
            int row = m0 + mb + i2*16 + q*4 + r;
            lg_part[((size_t)nblk * BB + row) * EE + l16] = lacc[i2][r];
        }
}

// ---------------- thinAc: combine sims+spec partials -> ss sigmoid -> xh/xl cols ----------------
__global__ __launch_bounds__(64)
void thinAc(const float* __restrict__ spec_part, const float* __restrict__ sims_part,
            const float* __restrict__ bs2,
            u16* __restrict__ xh_w, u16* __restrict__ xl_w)
{
    const int lane = threadIdx.x & 63;
    const int l16 = lane & 15, q = lane >> 4;
    const int m0 = blockIdx.x * 16;
    const float b2 = bs2[l16];
    #pragma unroll
    for (int r = 0; r < 4; ++r) {
        int row = m0 + q*4 + r;
        float sp = 0.0f;
        #pragma unroll
        for (int p = 0; p < 8; ++p) {
            sp += spec_part[((size_t)p * BB + row) * EE + l16];
            sp += sims_part[((size_t)p * BB + row) * EE + l16];
        }
        float ssv = 1.0f / (1.0f + expf(-(sp + b2)));
        u16 h = f2bf(ssv);
        xh_w[(size_t)row * KEXT + DD + l16] = h;
        xl_w[(size_t)row * KEXT + DD + l16] = f2bf(ssv - bf2f(h));
    }
}

// ---------------- thinBc: combine logit partials; softmax+top4+gates ----------------
__global__ __launch_bounds__(64)
void thinBc(const float* __restrict__ lg_part,
            const float* __restrict__ br2, const int* __restrict__ counters,
            float* __restrict__ out_gates, float* __restrict__ out_idx,
            float* __restrict__ out_probs)
{
    const int lane = threadIdx.x & 63;
    const int l16 = lane & 15, q = lane >> 4;
    const int m0 = blockIdx.x * 16;
    const float b2 = br2[l16];
    const int c2 = counters[0], c3 = counters[1];
    const int k = (c2 >= 8192) ? 1 : ((c3 >= 8192) ? 2 : 3);
    #pragma unroll
    for (int r = 0; r < 4; ++r) {
        const int row = m0 + q*4 + r;
        float lg = b2;
        #pragma unroll
        for (int p = 0; p < 8; ++p)
            lg += lg_part[((size_t)p * BB + row) * EE + l16];
        float mxv = lg;
        #pragma unroll
        for (int off = 1; off < 16; off <<= 1) mxv = fmaxf(mxv, __shfl_xor(mxv, off));
        float e = expf(lg - mxv);
        float den = e;
        #pragma unroll
        for (int off = 1; off < 16; off <<= 1) den += __shfl_xor(den, off);
        float p = e / den;
        out_probs[(size_t)row * EE + l16] = p;
        int kcur = (int)((__float_as_uint(p) & ~15u) | (15u - (unsigned)l16));
        float tv[4]; int ti[4];
        #pragma unroll
        for (int s = 0; s < 4; ++s) {
            int kk = kcur;
            #pragma unroll
            for (int off = 1; off < 16; off <<= 1) kk = max(kk, __shfl_xor(kk, off));
            int widx = 15 - (kk & 15);
            ti[s] = widx;
            tv[s] = __shfl(p, q * 16 + widx);
            if (l16 == widx) kcur = 0;
        }
        float den2 = 0.0f;
        float g[4];
        #pragma unroll
        for (int s = 0; s < 4; ++s) {
            g[s] = expf(tv[s] - tv[0]);
            if (s < k) den2 += g[s];
        }
        if (l16 < 4) {
            out_gates[(size_t)row * 4 + l16] = (l16 < k) ? g[l16] / den2 : 0.0f;
            out_idx[(size_t)row * 4 + l16] = (float)ti[l16];
        }
    }
}

// ---------------- host launch ----------------
extern "C" void kernel_launch(void* const* d_in, const int* in_sizes, int n_in,
                              void* d_out, int out_size, void* d_ws, size_t ws_size,
                              hipStream_t stream) {
    const float* x   = (const float*)d_in[0];
    const float* pat = (const float*)d_in[1];
    const float* Ws1 = (const float*)d_in[2];
    const float* bs1 = (const float*)d_in[3];
    const float* Ws2 = (const float*)d_in[4];
    const float* bs2 = (const float*)d_in[5];
    const float* Wr1 = (const float*)d_in[6];
    const float* br1 = (const float*)d_in[7];
    const float* Wr2 = (const float*)d_in[8];
    const float* br2 = (const float*)d_in[9];
    const float* Wk1 = (const float*)d_in[10];
    const float* bk1 = (const float*)d_in[11];
    const float* Wk2 = (const float*)d_in[12];
    const float* bk2 = (const float*)d_in[13];

    char* ws = (char*)d_ws;
    size_t off = 0;
    auto alloc = [&](size_t bytes) { char* p = ws + off; off += (bytes + 255) & ~(size_t)255; return p; };
    u16* xh     = (u16*)alloc((size_t)BB * KEXT * 2);
    u16* xl     = (u16*)alloc((size_t)BB * KEXT * 2);
    u16* w1t    = (u16*)alloc((size_t)HH * KEXT * 2);
    u16* wr1h   = (u16*)alloc((size_t)HH * KEXT * 2);
    u16* wr1l   = (u16*)alloc((size_t)HH * KEXT * 2);
    u16* w2t1   = (u16*)alloc((size_t)EE * HH * 2);
    u16* wr2th  = (u16*)alloc((size_t)EE * HH * 2);
    u16* wr2tl  = (u16*)alloc((size_t)EE * HH * 2);
    u16* patTh  = (u16*)alloc((size_t)EE * DD * 2);
    u16* patTl  = (u16*)alloc((size_t)EE * DD * 2);
    float* partA = (float*)alloc((size_t)16 * BB * EE * 4);  // spec(8) + sims(8) partials
    float* partB = (float*)alloc((size_t)8  * BB * EE * 4);  // logit partials
    unsigned* kflags = (unsigned*)alloc((size_t)BB * 4);
    int* cnt      = (int*)alloc(64);

    float* spec_part = partA;
    float* sims_part = partA + (size_t)8 * BB * EE;
    float* lg_part   = partB;

    float* out        = (float*)d_out;
    float* out_gates  = out;
    float* out_idx    = out + (size_t)BB * 4;
    float* out_probs  = out + (size_t)BB * 8;
    float* out_stats  = out + (size_t)BB * 24;

    // stats (4096 blocks) + weight prep (1584 blocks) co-scheduled
    stats_prep<<<4096 + 1584, 256, 0, stream>>>(
        x, Wk1, bk1, Wk2, bk2, out_stats, xh, xl, kflags,
        Ws1, Wr1, w1t, wr1h, wr1l, Ws2, Wr2, pat,
        w2t1, wr2th, wr2tl, patTh, patTl);

    kmed_kernel<<<1, 1024, 0, stream>>>(kflags, cnt);

    // h1 = relu(x@Ws1 + bs1), 128x128 tile, fused 3-term sims + spec partials
    gemm_h1<<<1024, 256, 0, stream>>>(xh, xl, w1t, bs1, w2t1, patTh, patTl,
                                      spec_part, sims_part);

    // combine partials -> ss sigmoid -> xh/xl cols 2048..2063
    thinAc<<<BB/16, 64, 0, stream>>>(spec_part, sims_part, bs2, xh, xl);

    // h2 = relu(ri@Wr1 + br1) 3-term with fused logit partials (h2 never hits global)
    gemm_h2<<<1024, 256, 0, stream>>>(xh, xl, wr1h, wr1l, br1, wr2th, wr2tl, lg_part);

    // combine logits + softmax + top4 + gates
    thinBc<<<BB/16, 64, 0, stream>>>(lg_part, br2, cnt, out_gates, out_idx, out_probs);
}